// Round 1
// baseline (196.914 us; speedup 1.0000x reference)
//
#include <hip/hip_runtime.h>

// WordSAGE on MI355X — fp32 in/out. Round-11 structure (2 kernels + memset):
//   k_prep : [edge fillpad x4/thread | gene->GH | weight pack]. The AF
//            fragment-reorder path is GONE: k_mega layer1 reads train fp32
//            directly and converts in-register (B1 is zero for k in [500,512),
//            so A pad values are don't-care).
//   k_mega : phase0 gather-mean from GH into LDS, then fused 4-layer
//            split-bf16 MFMA. Wave = col-group (8 groups); each wave covers
//            BOTH 16-row tiles -> every B byte read once per block.
// Precision: weights/agg/h split hi+lo bf16; train & gene hi-only (RNE).

#define NG 2500
#define NT 20000
#define NE 640000
#define NCLS 16
#define CAP 96

typedef unsigned short u16;
typedef unsigned int u32;

typedef float f32x4 __attribute__((ext_vector_type(4)));
typedef __bf16 bf16x8 __attribute__((ext_vector_type(8)));

__device__ __forceinline__ float b2f(u16 u) { return __uint_as_float(((u32)u) << 16); }
__device__ __forceinline__ float blo(u32 p) { return __uint_as_float(p << 16); }
__device__ __forceinline__ float bhi(u32 p) { return __uint_as_float(p & 0xffff0000u); }
__device__ __forceinline__ u16 f2b(float f) {  // RNE fp32->bf16
    u32 u = __float_as_uint(f);
    return (u16)((u + 0x7fffu + ((u >> 16) & 1u)) >> 16);
}

// native cast is RNE == f2b; compiler packs pairs into v_cvt_pk_bf16_f32
__device__ __forceinline__ bf16x8 pack8(float4 a, float4 b) {
    bf16x8 r;
    r[0] = (__bf16)a.x; r[1] = (__bf16)a.y; r[2] = (__bf16)a.z; r[3] = (__bf16)a.w;
    r[4] = (__bf16)b.x; r[5] = (__bf16)b.y; r[6] = (__bf16)b.z; r[7] = (__bf16)b.w;
    return r;
}

// ---- sizes ---------------------------------------------------------------
#define B1N 81920   // K=640: train k 0..499, zero 500..511, agg 512..639; N=128
#define B2N 32768   // K=256: h1 (W2s) 0..127, agg (W2n) 128..255; N=128
#define B3N 16384   // K=128 Wc1, N=128
#define B4N 2048    // K=128 Wc2, N=16
#define NEB 625     // edge blocks (4 edges/thread via int4)
#define GNB 625     // gene-convert blocks
#define PKB 520     // pack blocks

// ---- fused prep -----------------------------------------------------------
__global__ __launch_bounds__(256) void k_prep(
    const int* __restrict__ esrc, const int* __restrict__ edst,
    int* __restrict__ cnt, u16* __restrict__ csr,
    const float* __restrict__ gene, u32* __restrict__ GH32,
    const float* __restrict__ W1n, const float* __restrict__ W1s,
    const float* __restrict__ W2n, const float* __restrict__ W2s,
    const float* __restrict__ Wc1, const float* __restrict__ Wc2,
    u16* __restrict__ B1h, u16* __restrict__ B1l,
    u16* __restrict__ B2h, u16* __restrict__ B2l,
    u16* __restrict__ B3h, u16* __restrict__ B3l,
    u16* __restrict__ B4h, u16* __restrict__ B4l) {
    int blk = blockIdx.x, t = threadIdx.x;
    if (blk < NEB) {
        int e0 = (blk * 256 + t) * 4;
        const int4 s4 = *(const int4*)(esrc + e0);
        const int4 d4 = *(const int4*)(edst + e0);
        int ss[4] = {s4.x, s4.y, s4.z, s4.w};
        int dd[4] = {d4.x, d4.y, d4.z, d4.w};
#pragma unroll
        for (int i = 0; i < 4; ++i) {   // 4 independent atomic chains
            unsigned d = (unsigned)dd[i];
            if (d < NT) {
                int slot = atomicAdd(&cnt[d], 1);
                if (slot < CAP) csr[(size_t)d * CAP + slot] = (u16)ss[i];
            }
        }
        return;
    }
    if (blk < NEB + GNB) {
        int idx = (blk - NEB) * 256 + t;  // < 160000
        float2 v = ((const float2*)gene)[idx];
        GH32[idx] = (u32)f2b(v.x) | ((u32)f2b(v.y) << 16);
        return;
    }
    // ---- weight pack (split hi/lo, B-fragment order) ----
    int idx = (blk - NEB - GNB) * 256 + t;
    float v = 0.f;
    u16 *ph = 0, *pl = 0;
    int off = 0;
    if (idx < B1N) {
        int j = idx & 7, l = (idx >> 3) & 63, rest = idx >> 9;
        int g = rest & 7, kk = rest >> 3;
        int k = kk * 32 + ((l >> 4) << 3) + j, n = (g << 4) + (l & 15);
        if (k < 500) v = W1s[k * 128 + n];
        else if (k >= 512) v = W1n[(k - 512) * 128 + n];
        ph = B1h; pl = B1l; off = idx;
    } else if (idx < B1N + B2N) {
        int e = idx - B1N;
        int j = e & 7, l = (e >> 3) & 63, rest = e >> 9;
        int g = rest & 7, kk = rest >> 3;
        int k = kk * 32 + ((l >> 4) << 3) + j, n = (g << 4) + (l & 15);
        v = (k < 128) ? W2s[k * 128 + n] : W2n[(k - 128) * 128 + n];
        ph = B2h; pl = B2l; off = e;
    } else if (idx < B1N + B2N + B3N) {
        int e = idx - (B1N + B2N);
        int j = e & 7, l = (e >> 3) & 63, rest = e >> 9;
        int g = rest & 7, kk = rest >> 3;
        int k = kk * 32 + ((l >> 4) << 3) + j, n = (g << 4) + (l & 15);
        v = Wc1[k * 128 + n];
        ph = B3h; pl = B3l; off = e;
    } else if (idx < B1N + B2N + B3N + B4N) {
        int e = idx - (B1N + B2N + B3N);
        int j = e & 7, l = (e >> 3) & 63, kk = e >> 9;
        int k = kk * 32 + ((l >> 4) << 3) + j, n = l & 15;
        v = Wc2[k * 16 + n];
        ph = B4h; pl = B4l; off = e;
    }
    if (ph) {
        u16 hi = f2b(v);
        u16 lo = f2b(v - b2f(hi));
        ph[off] = hi;
        pl[off] = lo;
    }
}

// ---- fused gather + 4-layer MFMA ------------------------------------------
// Block: 512 thr (8 waves), 32 rows (2 tiles). wave = col-group g (0..7);
// each wave handles BOTH row-tiles (acc0/acc1) -> B bytes read once/block.
// Layer1 A comes straight from train (fp32 -> bf16 in-register).
__global__ __launch_bounds__(512) void k_mega(
    const int* __restrict__ cnt, const u16* __restrict__ csr,
    const u16* __restrict__ GH, const float* __restrict__ train,
    const u16* __restrict__ B1h, const u16* __restrict__ B1l,
    const u16* __restrict__ B2h, const u16* __restrict__ B2l,
    const u16* __restrict__ B3h, const u16* __restrict__ B3l,
    const u16* __restrict__ B4h, const u16* __restrict__ B4l,
    const float* __restrict__ b1, const float* __restrict__ b2,
    const float* __restrict__ bc1, const float* __restrict__ bc2,
    float* __restrict__ out) {
    __shared__ __align__(16) u16 SAGh[32 * 136], SAGl[32 * 136];
    __shared__ __align__(16) u16 S1h[32 * 136], S1l[32 * 136];
    __shared__ __align__(16) u16 S2h[32 * 136], S2l[32 * 136];
    int t = threadIdx.x;
    int row0 = blockIdx.x * 32;

    // ---- phase 0: gather-mean of gene-hi into SAG (agg hi/lo) ----
    {
        int r = t >> 4, cg = t & 15;           // row 0..31, col-group 0..15
        int d = row0 + r;
        int ctrue = cnt[d];
        int c = ctrue > CAP ? CAP : ctrue;
        const u16* crow = csr + (size_t)d * CAP;
        float a[8];
#pragma unroll
        for (int p = 0; p < 8; ++p) a[p] = 0.f;
        int j = 0;
        for (; j + 1 < c; j += 2) {
            int s0 = crow[j], s1 = crow[j + 1];
            uint4 p0 = *(const uint4*)(GH + (size_t)s0 * 128 + cg * 8);
            uint4 p1 = *(const uint4*)(GH + (size_t)s1 * 128 + cg * 8);
            a[0] += blo(p0.x); a[1] += bhi(p0.x);
            a[2] += blo(p0.y); a[3] += bhi(p0.y);
            a[4] += blo(p0.z); a[5] += bhi(p0.z);
            a[6] += blo(p0.w); a[7] += bhi(p0.w);
            a[0] += blo(p1.x); a[1] += bhi(p1.x);
            a[2] += blo(p1.y); a[3] += bhi(p1.y);
            a[4] += blo(p1.z); a[5] += bhi(p1.z);
            a[6] += blo(p1.w); a[7] += bhi(p1.w);
        }
        if (j < c) {
            int s = crow[j];
            uint4 p0 = *(const uint4*)(GH + (size_t)s * 128 + cg * 8);
            a[0] += blo(p0.x); a[1] += bhi(p0.x);
            a[2] += blo(p0.y); a[3] += bhi(p0.y);
            a[4] += blo(p0.z); a[5] += bhi(p0.z);
            a[6] += blo(p0.w); a[7] += bhi(p0.w);
        }
        float inv = (ctrue > 0) ? 1.f / (float)ctrue : 0.f;
        int base = (r * 136 + cg * 8) >> 1;    // u32 index (even)
        u32* SH = (u32*)SAGh;
        u32* SL = (u32*)SAGl;
#pragma unroll
        for (int p = 0; p < 4; ++p) {
            float x = a[2 * p] * inv, y = a[2 * p + 1] * inv;
            u16 hx = f2b(x), hy = f2b(y);
            SH[base + p] = (u32)hx | ((u32)hy << 16);
            SL[base + p] = (u32)f2b(x - b2f(hx)) | ((u32)f2b(y - b2f(hy)) << 16);
        }
    }
    __syncthreads();

    int lane = t & 63, g = t >> 6;  // wave index = col-group 0..7
    int m = lane & 15, q = lane >> 4, n16 = lane & 15;

    int hr0 = m * 136 + q * 8;
    int hr1 = (16 + m) * 136 + q * 8;
    int cr0 = q * 4, cr1 = 16 + q * 4;
    const f32x4 z4 = {0.f, 0.f, 0.f, 0.f};
    f32x4 acc0 = z4, acc1 = z4;

    // ---- layer1: K=640 (train fp32 direct kk0..15; agg hi+lo kk16..19 LDS) ----
    const float* tp0 = train + (size_t)(row0 + m) * 500 + q * 8;
    const float* tp1 = tp0 + 16 * 500;
#pragma unroll 4
    for (int kk = 0; kk < 15; ++kk) {
        float4 u0 = *(const float4*)(tp0 + kk * 32);
        float4 u1 = *(const float4*)(tp0 + kk * 32 + 4);
        float4 w0 = *(const float4*)(tp1 + kk * 32);
        float4 w1 = *(const float4*)(tp1 + kk * 32 + 4);
        size_t bo = ((size_t)(kk * 8 + g) * 64 + lane) * 8;
        bf16x8 bh = *(const bf16x8*)(B1h + bo);
        bf16x8 bl = *(const bf16x8*)(B1l + bo);
        bf16x8 a0 = pack8(u0, u1);
        bf16x8 a1 = pack8(w0, w1);
        acc0 = __builtin_amdgcn_mfma_f32_16x16x32_bf16(a0, bh, acc0, 0, 0, 0);
        acc0 = __builtin_amdgcn_mfma_f32_16x16x32_bf16(a0, bl, acc0, 0, 0, 0);
        acc1 = __builtin_amdgcn_mfma_f32_16x16x32_bf16(a1, bh, acc1, 0, 0, 0);
        acc1 = __builtin_amdgcn_mfma_f32_16x16x32_bf16(a1, bl, acc1, 0, 0, 0);
    }
    {   // kk=15 peeled: k 480..511; k>=500 multiplies zero B (pack pads 500..511
        // with 0), so clamped/garbage loads there are don't-care. Clamp keeps
        // the last rows' float4s in-bounds without corrupting real k<500 data.
        const u32 FMAX = (u32)NT * 500u - 4u;  // last valid float4 start
        u32 f0 = (u32)(row0 + m) * 500u + 480u + (u32)q * 8u;
        u32 f1 = f0 + 4u;
        u32 h0 = f0 + 8000u, h1 = h0 + 4u;
        f0 = f0 > FMAX ? FMAX : f0;
        f1 = f1 > FMAX ? FMAX : f1;
        h0 = h0 > FMAX ? FMAX : h0;
        h1 = h1 > FMAX ? FMAX : h1;
        float4 u0 = *(const float4*)(train + f0);
        float4 u1 = *(const float4*)(train + f1);
        float4 w0 = *(const float4*)(train + h0);
        float4 w1 = *(const float4*)(train + h1);
        size_t bo = ((size_t)(15 * 8 + g) * 64 + lane) * 8;
        bf16x8 bh = *(const bf16x8*)(B1h + bo);
        bf16x8 bl = *(const bf16x8*)(B1l + bo);
        bf16x8 a0 = pack8(u0, u1);
        bf16x8 a1 = pack8(w0, w1);
        acc0 = __builtin_amdgcn_mfma_f32_16x16x32_bf16(a0, bh, acc0, 0, 0, 0);
        acc0 = __builtin_amdgcn_mfma_f32_16x16x32_bf16(a0, bl, acc0, 0, 0, 0);
        acc1 = __builtin_amdgcn_mfma_f32_16x16x32_bf16(a1, bh, acc1, 0, 0, 0);
        acc1 = __builtin_amdgcn_mfma_f32_16x16x32_bf16(a1, bl, acc1, 0, 0, 0);
    }
#pragma unroll
    for (int kk = 16; kk < 20; ++kk) {
        int o = (kk - 16) * 32;
        bf16x8 ah0 = *(const bf16x8*)(SAGh + hr0 + o);
        bf16x8 al0 = *(const bf16x8*)(SAGl + hr0 + o);
        bf16x8 ah1 = *(const bf16x8*)(SAGh + hr1 + o);
        bf16x8 al1 = *(const bf16x8*)(SAGl + hr1 + o);
        size_t bo = ((size_t)(kk * 8 + g) * 64 + lane) * 8;
        bf16x8 bh = *(const bf16x8*)(B1h + bo);
        bf16x8 bl = *(const bf16x8*)(B1l + bo);
        acc0 = __builtin_amdgcn_mfma_f32_16x16x32_bf16(ah0, bh, acc0, 0, 0, 0);
        acc0 = __builtin_amdgcn_mfma_f32_16x16x32_bf16(ah0, bl, acc0, 0, 0, 0);
        acc0 = __builtin_amdgcn_mfma_f32_16x16x32_bf16(al0, bh, acc0, 0, 0, 0);
        acc1 = __builtin_amdgcn_mfma_f32_16x16x32_bf16(ah1, bh, acc1, 0, 0, 0);
        acc1 = __builtin_amdgcn_mfma_f32_16x16x32_bf16(ah1, bl, acc1, 0, 0, 0);
        acc1 = __builtin_amdgcn_mfma_f32_16x16x32_bf16(al1, bh, acc1, 0, 0, 0);
    }
    {
        int n = g * 16 + n16;
        float bias = b1[n];
#pragma unroll
        for (int rg = 0; rg < 4; ++rg) {
            float v0 = acc0[rg] + bias; v0 = v0 > 0.f ? v0 : 0.f;
            float v1 = acc1[rg] + bias; v1 = v1 > 0.f ? v1 : 0.f;
            u16 h0 = f2b(v0), h1v = f2b(v1);
            S1h[(cr0 + rg) * 136 + n] = h0; S1l[(cr0 + rg) * 136 + n] = f2b(v0 - b2f(h0));
            S1h[(cr1 + rg) * 136 + n] = h1v; S1l[(cr1 + rg) * 136 + n] = f2b(v1 - b2f(h1v));
        }
    }
    __syncthreads();

    // ---- layer2: K=256 (h1 kk0..3 S1; agg kk4..7 SAG) ----
    acc0 = z4; acc1 = z4;
#pragma unroll
    for (int kk = 0; kk < 8; ++kk) {
        const u16* Ph = (kk < 4) ? S1h : SAGh;
        const u16* Pl = (kk < 4) ? S1l : SAGl;
        int o = (kk & 3) * 32;
        bf16x8 ah0 = *(const bf16x8*)(Ph + hr0 + o);
        bf16x8 al0 = *(const bf16x8*)(Pl + hr0 + o);
        bf16x8 ah1 = *(const bf16x8*)(Ph + hr1 + o);
        bf16x8 al1 = *(const bf16x8*)(Pl + hr1 + o);
        size_t bo = ((size_t)(kk * 8 + g) * 64 + lane) * 8;
        bf16x8 bh = *(const bf16x8*)(B2h + bo);
        bf16x8 bl = *(const bf16x8*)(B2l + bo);
        acc0 = __builtin_amdgcn_mfma_f32_16x16x32_bf16(ah0, bh, acc0, 0, 0, 0);
        acc0 = __builtin_amdgcn_mfma_f32_16x16x32_bf16(ah0, bl, acc0, 0, 0, 0);
        acc0 = __builtin_amdgcn_mfma_f32_16x16x32_bf16(al0, bh, acc0, 0, 0, 0);
        acc1 = __builtin_amdgcn_mfma_f32_16x16x32_bf16(ah1, bh, acc1, 0, 0, 0);
        acc1 = __builtin_amdgcn_mfma_f32_16x16x32_bf16(ah1, bl, acc1, 0, 0, 0);
        acc1 = __builtin_amdgcn_mfma_f32_16x16x32_bf16(al1, bh, acc1, 0, 0, 0);
    }
    {
        int n = g * 16 + n16;
        float bias = b2[n];
#pragma unroll
        for (int rg = 0; rg < 4; ++rg) {
            float v0 = acc0[rg] + bias; v0 = v0 > 0.f ? v0 : 0.f;
            float v1 = acc1[rg] + bias; v1 = v1 > 0.f ? v1 : 0.f;
            u16 h0 = f2b(v0), h1v = f2b(v1);
            S2h[(cr0 + rg) * 136 + n] = h0; S2l[(cr0 + rg) * 136 + n] = f2b(v0 - b2f(h0));
            S2h[(cr1 + rg) * 136 + n] = h1v; S2l[(cr1 + rg) * 136 + n] = f2b(v1 - b2f(h1v));
        }
    }
    __syncthreads();

    // ---- layer3: K=128 (h2 S2) -> S1 ----
    acc0 = z4; acc1 = z4;
#pragma unroll
    for (int kk = 0; kk < 4; ++kk) {
        int o = kk * 32;
        bf16x8 ah0 = *(const bf16x8*)(S2h + hr0 + o);
        bf16x8 al0 = *(const bf16x8*)(S2l + hr0 + o);
        bf16x8 ah1 = *(const bf16x8*)(S2h + hr1 + o);
        bf16x8 al1 = *(const bf16x8*)(S2l + hr1 + o);
        size_t bo = ((size_t)(kk * 8 + g) * 64 + lane) * 8;
        bf16x8 bh = *(const bf16x8*)(B3h + bo);
        bf16x8 bl = *(const bf16x8*)(B3l + bo);
        acc0 = __builtin_amdgcn_mfma_f32_16x16x32_bf16(ah0, bh, acc0, 0, 0, 0);
        acc0 = __builtin_amdgcn_mfma_f32_16x16x32_bf16(ah0, bl, acc0, 0, 0, 0);
        acc0 = __builtin_amdgcn_mfma_f32_16x16x32_bf16(al0, bh, acc0, 0, 0, 0);
        acc1 = __builtin_amdgcn_mfma_f32_16x16x32_bf16(ah1, bh, acc1, 0, 0, 0);
        acc1 = __builtin_amdgcn_mfma_f32_16x16x32_bf16(ah1, bl, acc1, 0, 0, 0);
        acc1 = __builtin_amdgcn_mfma_f32_16x16x32_bf16(al1, bh, acc1, 0, 0, 0);
    }
    {
        int n = g * 16 + n16;
        float bias = bc1[n];
#pragma unroll
        for (int rg = 0; rg < 4; ++rg) {
            float v0 = acc0[rg] + bias; v0 = v0 > 0.f ? v0 : 0.f;
            float v1 = acc1[rg] + bias; v1 = v1 > 0.f ? v1 : 0.f;
            u16 h0 = f2b(v0), h1v = f2b(v1);
            S1h[(cr0 + rg) * 136 + n] = h0; S1l[(cr0 + rg) * 136 + n] = f2b(v0 - b2f(h0));
            S1h[(cr1 + rg) * 136 + n] = h1v; S1l[(cr1 + rg) * 136 + n] = f2b(v1 - b2f(h1v));
        }
    }
    __syncthreads();

    // ---- layer4: K=128, N=16 (waves 0,1 = tiles 0,1) ----
    if (g < 2) {
        int hr = (g == 0) ? hr0 : hr1;
        int cr = (g == 0) ? cr0 : cr1;
        f32x4 a4 = z4;
#pragma unroll
        for (int kk = 0; kk < 4; ++kk) {
            bf16x8 ah = *(const bf16x8*)(S1h + hr + kk * 32);
            bf16x8 al = *(const bf16x8*)(S1l + hr + kk * 32);
            size_t bo = ((size_t)kk * 64 + lane) * 8;
            bf16x8 bh = *(const bf16x8*)(B4h + bo);
            bf16x8 bl = *(const bf16x8*)(B4l + bo);
            a4 = __builtin_amdgcn_mfma_f32_16x16x32_bf16(ah, bh, a4, 0, 0, 0);
            a4 = __builtin_amdgcn_mfma_f32_16x16x32_bf16(ah, bl, a4, 0, 0, 0);
            a4 = __builtin_amdgcn_mfma_f32_16x16x32_bf16(al, bh, a4, 0, 0, 0);
        }
        float bias = bc2[n16];
#pragma unroll
        for (int rg = 0; rg < 4; ++rg)
            out[(size_t)(row0 + cr + rg) * NCLS + n16] = a4[rg] + bias;
    }
}

extern "C" void kernel_launch(void* const* d_in, const int* in_sizes, int n_in,
                              void* d_out, int out_size, void* d_ws, size_t ws_size,
                              hipStream_t stream) {
    const float* gene = (const float*)d_in[0];
    const float* train = (const float*)d_in[1];
    const int* esrc = (const int*)d_in[2];
    const int* edst = (const int*)d_in[3];

    char* ws = (char*)d_ws;
    int* cnt = (int*)(ws + 0);              //    80000
    u16* csr = (u16*)(ws + 80000);          //  3840000
    u16* GH = (u16*)(ws + 3920000);         //   640000 (2500*128 u16)
    u16* B1h = (u16*)(ws + 4560000);        //   163840
    u16* B1l = (u16*)(ws + 4723840);        //   163840
    u16* B2h = (u16*)(ws + 4887680);        //    65536
    u16* B2l = (u16*)(ws + 4953216);        //    65536
    u16* B3h = (u16*)(ws + 5018752);        //    32768
    u16* B3l = (u16*)(ws + 5051520);        //    32768
    u16* B4h = (u16*)(ws + 5084288);        //     4096
    u16* B4l = (u16*)(ws + 5088384);        //     4096
    // total 5,092,480 B

    hipMemsetAsync(cnt, 0, NT * sizeof(int), stream);
    k_prep<<<NEB + GNB + PKB, 256, 0, stream>>>(
        esrc, edst, cnt, csr, gene, (u32*)GH,
        (const float*)d_in[4], (const float*)d_in[5], (const float*)d_in[7],
        (const float*)d_in[8], (const float*)d_in[10], (const float*)d_in[12],
        B1h, B1l, B2h, B2l, B3h, B3l, B4h, B4l);
    k_mega<<<NT / 32, 512, 0, stream>>>(
        cnt, csr, GH, train, B1h, B1l, B2h, B2l, B3h, B3l, B4h, B4l,
        (const float*)d_in[6], (const float*)d_in[9], (const float*)d_in[11],
        (const float*)d_in[13], (float*)d_out);
}

// Round 2
// 167.608 us; speedup vs baseline: 1.1748x; 1.1748x over previous
//
#include <hip/hip_runtime.h>

// WordSAGE on MI355X — fp32 in/out. Round-12 structure (2 kernels + memset):
//   k_prep : [edge fillpad x4/thread | gene->GH | weight pack]. No AF.
//   k_mega : phase0 = {issue train-tile loads -> gather-mean from GH ->
//            convert+stage train tile bf16 in LDS (overlaid on S1/S2)},
//            then fused 4-layer split-bf16 MFMA. Layer1 A comes from the
//            LDS-staged tile (2 ds_read_b128/kk) instead of 4 global loads.
// Precision: weights/agg/h split hi+lo bf16; train & gene hi-only (RNE).

#define NG 2500
#define NT 20000
#define NE 640000
#define NCLS 16
#define CAP 96

typedef unsigned short u16;
typedef unsigned int u32;

typedef float f32x4 __attribute__((ext_vector_type(4)));
typedef __bf16 bf16x8 __attribute__((ext_vector_type(8)));

__device__ __forceinline__ float b2f(u16 u) { return __uint_as_float(((u32)u) << 16); }
__device__ __forceinline__ float blo(u32 p) { return __uint_as_float(p << 16); }
__device__ __forceinline__ float bhi(u32 p) { return __uint_as_float(p & 0xffff0000u); }
__device__ __forceinline__ u16 f2b(float f) {  // RNE fp32->bf16
    u32 u = __float_as_uint(f);
    return (u16)((u + 0x7fffu + ((u >> 16) & 1u)) >> 16);
}

// ---- sizes ---------------------------------------------------------------
#define B1N 81920   // K=640: train k 0..499, zero 500..511, agg 512..639; N=128
#define B2N 32768   // K=256: h1 (W2s) 0..127, agg (W2n) 128..255; N=128
#define B3N 16384   // K=128 Wc1, N=128
#define B4N 2048    // K=128 Wc2, N=16
#define NEB 625     // edge blocks (4 edges/thread via int4)
#define GNB 625     // gene-convert blocks
#define PKB 520     // pack blocks

// ---- fused prep -----------------------------------------------------------
__global__ __launch_bounds__(256) void k_prep(
    const int* __restrict__ esrc, const int* __restrict__ edst,
    int* __restrict__ cnt, u16* __restrict__ csr,
    const float* __restrict__ gene, u32* __restrict__ GH32,
    const float* __restrict__ W1n, const float* __restrict__ W1s,
    const float* __restrict__ W2n, const float* __restrict__ W2s,
    const float* __restrict__ Wc1, const float* __restrict__ Wc2,
    u16* __restrict__ B1h, u16* __restrict__ B1l,
    u16* __restrict__ B2h, u16* __restrict__ B2l,
    u16* __restrict__ B3h, u16* __restrict__ B3l,
    u16* __restrict__ B4h, u16* __restrict__ B4l) {
    int blk = blockIdx.x, t = threadIdx.x;
    if (blk < NEB) {
        int e0 = (blk * 256 + t) * 4;
        const int4 s4 = *(const int4*)(esrc + e0);
        const int4 d4 = *(const int4*)(edst + e0);
        int ss[4] = {s4.x, s4.y, s4.z, s4.w};
        int dd[4] = {d4.x, d4.y, d4.z, d4.w};
#pragma unroll
        for (int i = 0; i < 4; ++i) {   // 4 independent atomic chains
            unsigned d = (unsigned)dd[i];
            if (d < NT) {
                int slot = atomicAdd(&cnt[d], 1);
                if (slot < CAP) csr[(size_t)d * CAP + slot] = (u16)ss[i];
            }
        }
        return;
    }
    if (blk < NEB + GNB) {
        int idx = (blk - NEB) * 256 + t;  // < 160000
        float2 v = ((const float2*)gene)[idx];
        GH32[idx] = (u32)f2b(v.x) | ((u32)f2b(v.y) << 16);
        return;
    }
    // ---- weight pack (split hi/lo, B-fragment order) ----
    int idx = (blk - NEB - GNB) * 256 + t;
    float v = 0.f;
    u16 *ph = 0, *pl = 0;
    int off = 0;
    if (idx < B1N) {
        int j = idx & 7, l = (idx >> 3) & 63, rest = idx >> 9;
        int g = rest & 7, kk = rest >> 3;
        int k = kk * 32 + ((l >> 4) << 3) + j, n = (g << 4) + (l & 15);
        if (k < 500) v = W1s[k * 128 + n];
        else if (k >= 512) v = W1n[(k - 512) * 128 + n];
        ph = B1h; pl = B1l; off = idx;
    } else if (idx < B1N + B2N) {
        int e = idx - B1N;
        int j = e & 7, l = (e >> 3) & 63, rest = e >> 9;
        int g = rest & 7, kk = rest >> 3;
        int k = kk * 32 + ((l >> 4) << 3) + j, n = (g << 4) + (l & 15);
        v = (k < 128) ? W2s[k * 128 + n] : W2n[(k - 128) * 128 + n];
        ph = B2h; pl = B2l; off = e;
    } else if (idx < B1N + B2N + B3N) {
        int e = idx - (B1N + B2N);
        int j = e & 7, l = (e >> 3) & 63, rest = e >> 9;
        int g = rest & 7, kk = rest >> 3;
        int k = kk * 32 + ((l >> 4) << 3) + j, n = (g << 4) + (l & 15);
        v = Wc1[k * 128 + n];
        ph = B3h; pl = B3l; off = e;
    } else if (idx < B1N + B2N + B3N + B4N) {
        int e = idx - (B1N + B2N + B3N);
        int j = e & 7, l = (e >> 3) & 63, kk = e >> 9;
        int k = kk * 32 + ((l >> 4) << 3) + j, n = l & 15;
        v = Wc2[k * 16 + n];
        ph = B4h; pl = B4l; off = e;
    }
    if (ph) {
        u16 hi = f2b(v);
        u16 lo = f2b(v - b2f(hi));
        ph[off] = hi;
        pl[off] = lo;
    }
}

// ---- fused gather + stage + 4-layer MFMA ----------------------------------
// Block: 512 thr (8 waves), 32 rows (2 tiles). wave = col-group g (0..7);
// each wave handles BOTH row-tiles (acc0/acc1) -> B bytes read once/block.
// Shared pool (u16 units):
//   SAGh @0      [32*136]    SAGl @4352  [32*136]
//   S1h  @8704   [32*136]    S1l  @13056 [32*136]
//   S2h  @17408  [32*136]    S2l  @21760 [32*136]
//   TS   @8704   [32*520]  (train tile bf16, overlays S1h..S2l; dead after
//                           layer1 kk0..15 -> barrier before S1 epilogue)
__global__ __launch_bounds__(512) void k_mega(
    const int* __restrict__ cnt, const u16* __restrict__ csr,
    const u16* __restrict__ GH, const float* __restrict__ train,
    const u16* __restrict__ B1h, const u16* __restrict__ B1l,
    const u16* __restrict__ B2h, const u16* __restrict__ B2l,
    const u16* __restrict__ B3h, const u16* __restrict__ B3l,
    const u16* __restrict__ B4h, const u16* __restrict__ B4l,
    const float* __restrict__ b1, const float* __restrict__ b2,
    const float* __restrict__ bc1, const float* __restrict__ bc2,
    float* __restrict__ out) {
    __shared__ __align__(16) u16 SMEM[26112];   // 52224 B, same as round 11
    u16* SAGh = SMEM;
    u16* SAGl = SMEM + 4352;
    u16* S1h = SMEM + 8704;
    u16* S1l = SMEM + 13056;
    u16* S2h = SMEM + 17408;
    u16* S2l = SMEM + 21760;
    u16* TS = SMEM + 8704;                      // overlays S1h..S2l

    int t = threadIdx.x;
    int row0 = blockIdx.x * 32;

    // ---- phase 0a: issue train-tile loads (latency hides under gather) ----
    float4 st[8];
    {
        const float4* tb = (const float4*)(train + (size_t)row0 * 500);
#pragma unroll
        for (int i = 0; i < 7; ++i) st[i] = tb[t + i * 512];
        if (t < 416) st[7] = tb[t + 3584];      // 4000 float4 = 32 rows x 125
    }

    // ---- phase 0b: gather-mean of gene-hi into SAG (agg hi/lo) ----
    {
        int r = t >> 4, cg = t & 15;           // row 0..31, col-group 0..15
        int d = row0 + r;
        int ctrue = cnt[d];
        int c = ctrue > CAP ? CAP : ctrue;
        const u16* crow = csr + (size_t)d * CAP;
        float a[8];
#pragma unroll
        for (int p = 0; p < 8; ++p) a[p] = 0.f;
        int j = 0;
        for (; j + 1 < c; j += 2) {
            int s0 = crow[j], s1 = crow[j + 1];
            uint4 p0 = *(const uint4*)(GH + (size_t)s0 * 128 + cg * 8);
            uint4 p1 = *(const uint4*)(GH + (size_t)s1 * 128 + cg * 8);
            a[0] += blo(p0.x); a[1] += bhi(p0.x);
            a[2] += blo(p0.y); a[3] += bhi(p0.y);
            a[4] += blo(p0.z); a[5] += bhi(p0.z);
            a[6] += blo(p0.w); a[7] += bhi(p0.w);
            a[0] += blo(p1.x); a[1] += bhi(p1.x);
            a[2] += blo(p1.y); a[3] += bhi(p1.y);
            a[4] += blo(p1.z); a[5] += bhi(p1.z);
            a[6] += blo(p1.w); a[7] += bhi(p1.w);
        }
        if (j < c) {
            int s = crow[j];
            uint4 p0 = *(const uint4*)(GH + (size_t)s * 128 + cg * 8);
            a[0] += blo(p0.x); a[1] += bhi(p0.x);
            a[2] += blo(p0.y); a[3] += bhi(p0.y);
            a[4] += blo(p0.z); a[5] += bhi(p0.z);
            a[6] += blo(p0.w); a[7] += bhi(p0.w);
        }
        float inv = (ctrue > 0) ? 1.f / (float)ctrue : 0.f;
        int base = (r * 136 + cg * 8) >> 1;    // u32 index (even)
        u32* SH = (u32*)SAGh;
        u32* SL = (u32*)SAGl;
#pragma unroll
        for (int p = 0; p < 4; ++p) {
            float x = a[2 * p] * inv, y = a[2 * p + 1] * inv;
            u16 hx = f2b(x), hy = f2b(y);
            SH[base + p] = (u32)hx | ((u32)hy << 16);
            SL[base + p] = (u32)f2b(x - b2f(hx)) | ((u32)f2b(y - b2f(hy)) << 16);
        }
    }

    // ---- phase 0c: convert staged tile -> TS (row-major [32][520] bf16) ----
    {
        u32* T32 = (u32*)TS;
#pragma unroll
        for (int i = 0; i < 8; ++i) {
            int idx = t + i * 512;
            if (i == 7 && t >= 416) break;
            int r = idx / 125, c4 = idx - r * 125;
            int base = r * 260 + c4 * 2;       // u32 units; row stride 520 u16
            T32[base] = (u32)f2b(st[i].x) | ((u32)f2b(st[i].y) << 16);
            T32[base + 1] = (u32)f2b(st[i].z) | ((u32)f2b(st[i].w) << 16);
        }
        if (t < 192) {                          // zero cols 500..511
            int r = t / 6, c = t - r * 6;
            T32[r * 260 + 250 + c] = 0;
        }
    }
    __syncthreads();

    int lane = t & 63, g = t >> 6;  // wave index = col-group 0..7
    int m = lane & 15, q = lane >> 4, n16 = lane & 15;

    int hr0 = m * 136 + q * 8;
    int hr1 = (16 + m) * 136 + q * 8;
    int cr0 = q * 4, cr1 = 16 + q * 4;
    const f32x4 z4 = {0.f, 0.f, 0.f, 0.f};
    f32x4 acc0 = z4, acc1 = z4;

    // ---- layer1: K=640 (train bf16 kk0..15 from TS; agg kk16..19 SAG) ----
    const u16* tA0 = TS + m * 520 + q * 8;
    const u16* tA1 = TS + (16 + m) * 520 + q * 8;
#pragma unroll
    for (int kk = 0; kk < 16; ++kk) {
        bf16x8 a0 = *(const bf16x8*)(tA0 + kk * 32);
        bf16x8 a1 = *(const bf16x8*)(tA1 + kk * 32);
        size_t bo = ((size_t)(kk * 8 + g) * 64 + lane) * 8;
        bf16x8 bh = *(const bf16x8*)(B1h + bo);
        bf16x8 bl = *(const bf16x8*)(B1l + bo);
        acc0 = __builtin_amdgcn_mfma_f32_16x16x32_bf16(a0, bh, acc0, 0, 0, 0);
        acc0 = __builtin_amdgcn_mfma_f32_16x16x32_bf16(a0, bl, acc0, 0, 0, 0);
        acc1 = __builtin_amdgcn_mfma_f32_16x16x32_bf16(a1, bh, acc1, 0, 0, 0);
        acc1 = __builtin_amdgcn_mfma_f32_16x16x32_bf16(a1, bl, acc1, 0, 0, 0);
    }
#pragma unroll
    for (int kk = 16; kk < 20; ++kk) {
        int o = (kk - 16) * 32;
        bf16x8 ah0 = *(const bf16x8*)(SAGh + hr0 + o);
        bf16x8 al0 = *(const bf16x8*)(SAGl + hr0 + o);
        bf16x8 ah1 = *(const bf16x8*)(SAGh + hr1 + o);
        bf16x8 al1 = *(const bf16x8*)(SAGl + hr1 + o);
        size_t bo = ((size_t)(kk * 8 + g) * 64 + lane) * 8;
        bf16x8 bh = *(const bf16x8*)(B1h + bo);
        bf16x8 bl = *(const bf16x8*)(B1l + bo);
        acc0 = __builtin_amdgcn_mfma_f32_16x16x32_bf16(ah0, bh, acc0, 0, 0, 0);
        acc0 = __builtin_amdgcn_mfma_f32_16x16x32_bf16(ah0, bl, acc0, 0, 0, 0);
        acc0 = __builtin_amdgcn_mfma_f32_16x16x32_bf16(al0, bh, acc0, 0, 0, 0);
        acc1 = __builtin_amdgcn_mfma_f32_16x16x32_bf16(ah1, bh, acc1, 0, 0, 0);
        acc1 = __builtin_amdgcn_mfma_f32_16x16x32_bf16(ah1, bl, acc1, 0, 0, 0);
        acc1 = __builtin_amdgcn_mfma_f32_16x16x32_bf16(al1, bh, acc1, 0, 0, 0);
    }
    __syncthreads();   // TS (overlaid on S1/S2) dead only when ALL waves passed
    {
        int n = g * 16 + n16;
        float bias = b1[n];
#pragma unroll
        for (int rg = 0; rg < 4; ++rg) {
            float v0 = acc0[rg] + bias; v0 = v0 > 0.f ? v0 : 0.f;
            float v1 = acc1[rg] + bias; v1 = v1 > 0.f ? v1 : 0.f;
            u16 h0 = f2b(v0), h1v = f2b(v1);
            S1h[(cr0 + rg) * 136 + n] = h0; S1l[(cr0 + rg) * 136 + n] = f2b(v0 - b2f(h0));
            S1h[(cr1 + rg) * 136 + n] = h1v; S1l[(cr1 + rg) * 136 + n] = f2b(v1 - b2f(h1v));
        }
    }
    __syncthreads();

    // ---- layer2: K=256 (h1 kk0..3 S1; agg kk4..7 SAG) ----
    acc0 = z4; acc1 = z4;
#pragma unroll
    for (int kk = 0; kk < 8; ++kk) {
        const u16* Ph = (kk < 4) ? S1h : SAGh;
        const u16* Pl = (kk < 4) ? S1l : SAGl;
        int o = (kk & 3) * 32;
        bf16x8 ah0 = *(const bf16x8*)(Ph + hr0 + o);
        bf16x8 al0 = *(const bf16x8*)(Pl + hr0 + o);
        bf16x8 ah1 = *(const bf16x8*)(Ph + hr1 + o);
        bf16x8 al1 = *(const bf16x8*)(Pl + hr1 + o);
        size_t bo = ((size_t)(kk * 8 + g) * 64 + lane) * 8;
        bf16x8 bh = *(const bf16x8*)(B2h + bo);
        bf16x8 bl = *(const bf16x8*)(B2l + bo);
        acc0 = __builtin_amdgcn_mfma_f32_16x16x32_bf16(ah0, bh, acc0, 0, 0, 0);
        acc0 = __builtin_amdgcn_mfma_f32_16x16x32_bf16(ah0, bl, acc0, 0, 0, 0);
        acc0 = __builtin_amdgcn_mfma_f32_16x16x32_bf16(al0, bh, acc0, 0, 0, 0);
        acc1 = __builtin_amdgcn_mfma_f32_16x16x32_bf16(ah1, bh, acc1, 0, 0, 0);
        acc1 = __builtin_amdgcn_mfma_f32_16x16x32_bf16(ah1, bl, acc1, 0, 0, 0);
        acc1 = __builtin_amdgcn_mfma_f32_16x16x32_bf16(al1, bh, acc1, 0, 0, 0);
    }
    {
        int n = g * 16 + n16;
        float bias = b2[n];
#pragma unroll
        for (int rg = 0; rg < 4; ++rg) {
            float v0 = acc0[rg] + bias; v0 = v0 > 0.f ? v0 : 0.f;
            float v1 = acc1[rg] + bias; v1 = v1 > 0.f ? v1 : 0.f;
            u16 h0 = f2b(v0), h1v = f2b(v1);
            S2h[(cr0 + rg) * 136 + n] = h0; S2l[(cr0 + rg) * 136 + n] = f2b(v0 - b2f(h0));
            S2h[(cr1 + rg) * 136 + n] = h1v; S2l[(cr1 + rg) * 136 + n] = f2b(v1 - b2f(h1v));
        }
    }
    __syncthreads();

    // ---- layer3: K=128 (h2 S2) -> S1 ----
    acc0 = z4; acc1 = z4;
#pragma unroll
    for (int kk = 0; kk < 4; ++kk) {
        int o = kk * 32;
        bf16x8 ah0 = *(const bf16x8*)(S2h + hr0 + o);
        bf16x8 al0 = *(const bf16x8*)(S2l + hr0 + o);
        bf16x8 ah1 = *(const bf16x8*)(S2h + hr1 + o);
        bf16x8 al1 = *(const bf16x8*)(S2l + hr1 + o);
        size_t bo = ((size_t)(kk * 8 + g) * 64 + lane) * 8;
        bf16x8 bh = *(const bf16x8*)(B3h + bo);
        bf16x8 bl = *(const bf16x8*)(B3l + bo);
        acc0 = __builtin_amdgcn_mfma_f32_16x16x32_bf16(ah0, bh, acc0, 0, 0, 0);
        acc0 = __builtin_amdgcn_mfma_f32_16x16x32_bf16(ah0, bl, acc0, 0, 0, 0);
        acc0 = __builtin_amdgcn_mfma_f32_16x16x32_bf16(al0, bh, acc0, 0, 0, 0);
        acc1 = __builtin_amdgcn_mfma_f32_16x16x32_bf16(ah1, bh, acc1, 0, 0, 0);
        acc1 = __builtin_amdgcn_mfma_f32_16x16x32_bf16(ah1, bl, acc1, 0, 0, 0);
        acc1 = __builtin_amdgcn_mfma_f32_16x16x32_bf16(al1, bh, acc1, 0, 0, 0);
    }
    {
        int n = g * 16 + n16;
        float bias = bc1[n];
#pragma unroll
        for (int rg = 0; rg < 4; ++rg) {
            float v0 = acc0[rg] + bias; v0 = v0 > 0.f ? v0 : 0.f;
            float v1 = acc1[rg] + bias; v1 = v1 > 0.f ? v1 : 0.f;
            u16 h0 = f2b(v0), h1v = f2b(v1);
            S1h[(cr0 + rg) * 136 + n] = h0; S1l[(cr0 + rg) * 136 + n] = f2b(v0 - b2f(h0));
            S1h[(cr1 + rg) * 136 + n] = h1v; S1l[(cr1 + rg) * 136 + n] = f2b(v1 - b2f(h1v));
        }
    }
    __syncthreads();

    // ---- layer4: K=128, N=16 (waves 0,1 = tiles 0,1) ----
    if (g < 2) {
        int hr = (g == 0) ? hr0 : hr1;
        int cr = (g == 0) ? cr0 : cr1;
        f32x4 a4 = z4;
#pragma unroll
        for (int kk = 0; kk < 4; ++kk) {
            bf16x8 ah = *(const bf16x8*)(S1h + hr + kk * 32);
            bf16x8 al = *(const bf16x8*)(S1l + hr + kk * 32);
            size_t bo = ((size_t)kk * 64 + lane) * 8;
            bf16x8 bh = *(const bf16x8*)(B4h + bo);
            bf16x8 bl = *(const bf16x8*)(B4l + bo);
            a4 = __builtin_amdgcn_mfma_f32_16x16x32_bf16(ah, bh, a4, 0, 0, 0);
            a4 = __builtin_amdgcn_mfma_f32_16x16x32_bf16(ah, bl, a4, 0, 0, 0);
            a4 = __builtin_amdgcn_mfma_f32_16x16x32_bf16(al, bh, a4, 0, 0, 0);
        }
        float bias = bc2[n16];
#pragma unroll
        for (int rg = 0; rg < 4; ++rg)
            out[(size_t)(row0 + cr + rg) * NCLS + n16] = a4[rg] + bias;
    }
}

extern "C" void kernel_launch(void* const* d_in, const int* in_sizes, int n_in,
                              void* d_out, int out_size, void* d_ws, size_t ws_size,
                              hipStream_t stream) {
    const float* gene = (const float*)d_in[0];
    const float* train = (const float*)d_in[1];
    const int* esrc = (const int*)d_in[2];
    const int* edst = (const int*)d_in[3];

    char* ws = (char*)d_ws;
    int* cnt = (int*)(ws + 0);              //    80000
    u16* csr = (u16*)(ws + 80000);          //  3840000
    u16* GH = (u16*)(ws + 3920000);         //   640000 (2500*128 u16)
    u16* B1h = (u16*)(ws + 4560000);        //   163840
    u16* B1l = (u16*)(ws + 4723840);        //   163840
    u16* B2h = (u16*)(ws + 4887680);        //    65536
    u16* B2l = (u16*)(ws + 4953216);        //    65536
    u16* B3h = (u16*)(ws + 5018752);        //    32768
    u16* B3l = (u16*)(ws + 5051520);        //    32768
    u16* B4h = (u16*)(ws + 5084288);        //     4096
    u16* B4l = (u16*)(ws + 5088384);        //     4096
    // total 5,092,480 B

    hipMemsetAsync(cnt, 0, NT * sizeof(int), stream);
    k_prep<<<NEB + GNB + PKB, 256, 0, stream>>>(
        esrc, edst, cnt, csr, gene, (u32*)GH,
        (const float*)d_in[4], (const float*)d_in[5], (const float*)d_in[7],
        (const float*)d_in[8], (const float*)d_in[10], (const float*)d_in[12],
        B1h, B1l, B2h, B2l, B3h, B3l, B4h, B4l);
    k_mega<<<NT / 32, 512, 0, stream>>>(
        cnt, csr, GH, train, B1h, B1l, B2h, B2l, B3h, B3l, B4h, B4l,
        (const float*)d_in[6], (const float*)d_in[9], (const float*)d_in[11],
        (const float*)d_in[13], (float*)d_out);
}